// Round 17
// baseline (437.658 us; speedup 1.0000x reference)
//
#include <hip/hip_runtime.h>
#include <hip/hip_fp16.h>

#define DIM 64
#define BOT 15
#define NLAYERS 5
#define BN_EPS 1e-5f
#define ROWS 64            // stats_k rows per block (512 threads)
#define ROWS_FB 32         // fallback layer_k rows per block
#define BKT_SHIFT 8        // bucket = dst >> 8
#define NSTRIPE 4          // gsum contention stripes

__device__ inline void fma4(float4& acc, const float4& a, float s) {
    acc.x = fmaf(a.x, s, acc.x); acc.y = fmaf(a.y, s, acc.y);
    acc.z = fmaf(a.z, s, acc.z); acc.w = fmaf(a.w, s, acc.w);
}
__device__ inline void add4(float4& acc, const float4& a) {
    acc.x += a.x; acc.y += a.y; acc.z += a.z; acc.w += a.w;
}
__device__ inline void fma4sq(float4& acc, const float4& a) {
    acc.x = fmaf(a.x, a.x, acc.x); acc.y = fmaf(a.y, a.y, acc.y);
    acc.z = fmaf(a.z, a.z, acc.z); acc.w = fmaf(a.w, a.w, acc.w);
}
__device__ inline void wavered4(float4& v) {
    v.x += __shfl_xor(v.x, 16); v.y += __shfl_xor(v.y, 16);
    v.z += __shfl_xor(v.z, 16); v.w += __shfl_xor(v.w, 16);
    v.x += __shfl_xor(v.x, 32); v.y += __shfl_xor(v.y, 32);
    v.z += __shfl_xor(v.z, 32); v.w += __shfl_xor(v.w, 32);
}
__device__ inline uint2 packh4(const float4& v) {
    __half2 a = __floats2half2_rn(v.x, v.y);
    __half2 b = __floats2half2_rn(v.z, v.w);
    uint2 pk;
    pk.x = *(unsigned int*)&a;
    pk.y = *(unsigned int*)&b;
    return pk;
}
__device__ inline float4 unpackh4(uint2 pk) {
    __half2 a = *(__half2*)&pk.x;
    __half2 b = *(__half2*)&pk.y;
    float4 v;
    v.x = __low2float(a); v.y = __high2float(a);
    v.z = __low2float(b); v.w = __high2float(b);
    return v;
}

// ---------------- CSR build ----------------

__global__ __launch_bounds__(256) void hist_k(const int* __restrict__ dst,
                                              int* __restrict__ deg, int E) {
    int e = blockIdx.x * blockDim.x + threadIdx.x;
    if (e < E) atomicAdd(&deg[dst[e]], 1);
}

__global__ __launch_bounds__(1024) void scan_part_k(const int* __restrict__ deg,
                                                    int* __restrict__ excl,
                                                    int* __restrict__ bsum, int n) {
    __shared__ int buf[1024];
    int t = threadIdx.x;
    int idx = blockIdx.x * 1024 + t;
    int v = (idx < n) ? deg[idx] : 0;
    buf[t] = v;
    __syncthreads();
    for (int off = 1; off < 1024; off <<= 1) {
        int x = (t >= off) ? buf[t - off] : 0;
        __syncthreads();
        buf[t] += x;
        __syncthreads();
    }
    if (idx < n) excl[idx] = buf[t] - v;
    if (t == 0) bsum[blockIdx.x] = buf[1023];
}

__global__ __launch_bounds__(1024) void scan_top_k(const int* __restrict__ bsum,
                                                   int* __restrict__ boff, int nb,
                                                   int* __restrict__ row_ptr, int n) {
    __shared__ int buf[1024];
    int t = threadIdx.x;
    int v = (t < nb) ? bsum[t] : 0;
    buf[t] = v;
    __syncthreads();
    for (int off = 1; off < 1024; off <<= 1) {
        int x = (t >= off) ? buf[t - off] : 0;
        __syncthreads();
        buf[t] += x;
        __syncthreads();
    }
    if (t < nb) boff[t] = buf[t] - v;
    if (t == 1023) row_ptr[n] = buf[1023];
}

__global__ __launch_bounds__(256) void scan_add_k(int* __restrict__ row_ptr,
                                                  const int* __restrict__ boff,
                                                  int* __restrict__ deg,
                                                  int* __restrict__ bcur, int n) {
    int i = blockIdx.x * blockDim.x + threadIdx.x;
    if (i < n) {
        int v = row_ptr[i] + boff[i >> 10];
        row_ptr[i] = v;
        deg[i] = v;
        if ((i & 255) == 0) bcur[i >> BKT_SHIFT] = v;
    }
}

// fallback flat scatter (small-ws path)
__global__ __launch_bounds__(256) void scatter_k(const int* __restrict__ src,
                                                 const int* __restrict__ dst,
                                                 int* __restrict__ cursor,
                                                 int* __restrict__ csr, int E) {
    int e = blockIdx.x * blockDim.x + threadIdx.x;
    if (e < E) {
        int p = atomicAdd(&cursor[dst[e]], 1);
        csr[p] = src[e];
    }
}

// phase A: LDS-binned partition of edges into dst-buckets
__global__ __launch_bounds__(256) void part_k(const int* __restrict__ src,
                                              const int* __restrict__ dst,
                                              int* __restrict__ bcur,
                                              int2* __restrict__ part, int E) {
    __shared__ int hist[256];
    __shared__ int cur[256];
    int t = threadIdx.x;
    int base = blockIdx.x * 2048;
    hist[t] = 0;
    __syncthreads();
    int2 ed[8];
    int bk[8];
    #pragma unroll
    for (int k = 0; k < 8; k++) {
        int i = base + k * 256 + t;
        if (i < E) {
            ed[k].x = src[i];
            ed[k].y = dst[i];
            bk[k] = ed[k].y >> BKT_SHIFT;
            atomicAdd(&hist[bk[k]], 1);
        } else bk[k] = -1;
    }
    __syncthreads();
    int h = hist[t];
    if (h > 0) cur[t] = atomicAdd(&bcur[t], h);
    __syncthreads();
    #pragma unroll
    for (int k = 0; k < 8; k++) {
        if (bk[k] >= 0) {
            int p = atomicAdd(&cur[bk[k]], 1);
            part[p] = ed[k];
        }
    }
}

// phase B: one block per bucket
__global__ __launch_bounds__(256) void bscat_k(const int2* __restrict__ part,
                                               const int* __restrict__ row_ptr,
                                               int* __restrict__ cursor,
                                               int* __restrict__ csr, int n) {
    int b = blockIdx.x;
    int lo = row_ptr[b << BKT_SHIFT];
    int hiN = (b + 1) << BKT_SHIFT;
    int hi = row_ptr[hiN < n ? hiN : n];
    for (int i = lo + (int)threadIdx.x; i < hi; i += 256) {
        int2 e = part[i];
        int p = atomicAdd(&cursor[e.y], 1);
        csr[p] = e.x;
    }
}

// ---------------- f32 -> fp16 mirror ----------------

__global__ __launch_bounds__(256) void tohalf_k(const float* __restrict__ x,
                                                __half* __restrict__ hh, int n4) {
    int i = blockIdx.x * blockDim.x + threadIdx.x;
    if (i >= n4) return;
    float4 v = *(const float4*)&x[(size_t)i * 4];
    *(uint2*)&hh[(size_t)i * 4] = packh4(v);
}

// ---------------- aggregation (fp16 gather, fp16 store) ----------------

__global__ __launch_bounds__(256) void aggr_h_k(const __half* __restrict__ hh,
                                                const int* __restrict__ row_ptr,
                                                const int* __restrict__ csr,
                                                __half* __restrict__ ah, int n) {
    int gid = blockIdx.x * blockDim.x + threadIdx.x;
    int node = gid >> 6;
    int lane = threadIdx.x & 63;
    if (node >= n) return;
    int j = lane >> 3, q = lane & 7;
    int s = row_ptr[node], e = row_ptr[node + 1];
    float acc[8] = {0.f, 0.f, 0.f, 0.f, 0.f, 0.f, 0.f, 0.f};
    #pragma unroll 2
    for (int i = s; i < e; i += 8) {
        int ii = i + j;
        if (ii < e) {
            int idx = csr[ii];
            uint4 raw = *(const uint4*)&hh[(size_t)idx * DIM + q * 8];
            const __half2* hp = (const __half2*)&raw;
            #pragma unroll
            for (int k = 0; k < 4; k++) {
                acc[2 * k]     += __low2float(hp[k]);
                acc[2 * k + 1] += __high2float(hp[k]);
            }
        }
    }
    #pragma unroll
    for (int off = 8; off <= 32; off <<= 1) {
        #pragma unroll
        for (int k = 0; k < 8; k++) acc[k] += __shfl_xor(acc[k], off);
    }
    if (lane < 8) {
        float4 a = {acc[0], acc[1], acc[2], acc[3]};
        float4 b = {acc[4], acc[5], acc[6], acc[7]};
        uint2 pa = packh4(a), pb = packh4(b);
        uint4 pk = {pa.x, pa.y, pb.x, pb.y};
        *(uint4*)&ah[(size_t)node * DIM + q * 8] = pk;
    }
}

// fallback f32 gather
__global__ __launch_bounds__(256) void aggr_k(const float* __restrict__ h,
                                              const int* __restrict__ row_ptr,
                                              const int* __restrict__ csr,
                                              float* __restrict__ out, int n) {
    int gid = blockIdx.x * blockDim.x + threadIdx.x;
    int node = gid >> 6;
    int lane = threadIdx.x & 63;
    if (node >= n) return;
    int j = lane >> 4, q = lane & 15;
    int s = row_ptr[node], e = row_ptr[node + 1];
    float4 acc = {0.f, 0.f, 0.f, 0.f};
    #pragma unroll 4
    for (int i = s; i < e; i += 4) {
        int ii = i + j;
        if (ii < e) {
            int idx = csr[ii];
            float4 v = *(const float4*)&h[(size_t)idx * DIM + q * 4];
            add4(acc, v);
        }
    }
    wavered4(acc);
    if (lane < 16) *(float4*)&out[(size_t)node * DIM + q * 4] = acc;
}

// ---------------- stats pass v6: fp16 LDS (47 KB) + VGPR cap for 3 blocks/CU ----
// xa/wc/p1t/p2 staged fp16 in LDS (compute in f32 after unpack); m_s/red_s f32.
// launch_bounds(512,6): VGPR <= ~85 so 24 waves/CU actually materialize.

__global__ __launch_bounds__(512, 6) void stats_k(
    const __half* __restrict__ hh, const __half* __restrict__ ah,
    const float* __restrict__ Wc, const float* __restrict__ bc,
    const float* __restrict__ p1a, const float* __restrict__ b1a,
    const float* __restrict__ p2a, const float* __restrict__ b2a,
    const float* __restrict__ p1b, const float* __restrict__ b1b,
    const float* __restrict__ p2b, const float* __restrict__ b2b,
    float* __restrict__ gsum,          // [NSTRIPE][6][64], pre-zeroed
    __half* __restrict__ yh, __half* __restrict__ uh, __half* __restrict__ vh,
    int n) {
    __shared__ __half xa_s[ROWS][72];      // 9.2 KB (stride 144B, 8B-aligned reads)
    __shared__ __half wc_s[64][68];        // 8.7 KB
    __shared__ __half p1t_s[2][15][72];    // 4.3 KB, transposed [m][k]
    __shared__ __half p2_s[2][15][64];     // 3.8 KB
    __shared__ float m_s[2][ROWS][17];     // 8.7 KB
    __shared__ float red_s[6][8][64];      // 12.3 KB

    int t = threadIdx.x;
    int rowBase = blockIdx.x * ROWS;

    // ---- stage xa: fp16 global -> fp16 LDS (straight uint2 copy) ----
    #pragma unroll
    for (int i = 0; i < 2; i++) {
        int idx = t + i * 512;
        int r = idx >> 4, c4 = (idx & 15) * 4;
        int gr = rowBase + r;
        uint2 va = {0u, 0u};
        if (gr < n) va = *(const uint2*)&ah[(size_t)gr * DIM + c4];
        *(uint2*)&xa_s[r][c4] = va;
    }
    // ---- stage Wc: f32 -> fp16 ----
    #pragma unroll
    for (int i = 0; i < 2; i++) {
        int idx = t + i * 512;
        int k = idx >> 4, c4 = (idx & 15) * 4;
        float4 w = *(const float4*)&Wc[k * DIM + c4];
        *(uint2*)&wc_s[k][c4] = packh4(w);
    }
    // ---- stage p2 (both branches): f32 -> fp16 ----
    if (t < 240) {
        int m = t >> 4, c4 = (t & 15) * 4;
        float4 wa = *(const float4*)&p2a[m * DIM + c4];
        float4 wb = *(const float4*)&p2b[m * DIM + c4];
        *(uint2*)&p2_s[0][m][c4] = packh4(wa);
        *(uint2*)&p2_s[1][m][c4] = packh4(wb);
    }
    // ---- stage p1 transposed: global [k][m] f32 -> LDS [m][k] fp16 ----
    #pragma unroll
    for (int i = 0; i < 2; i++) {
        int idx = t + i * 512;
        if (idx < 960) {
            int k = idx / 15, m = idx % 15;
            p1t_s[0][m][k] = __float2half(p1a[idx]);
            p1t_s[1][m][k] = __float2half(p1b[idx]);
        }
    }
    __syncthreads();

    // ---- phase 1: bottleneck mids (fp16 inputs, f32 accumulate) ----
    {
        int m = t & 15, r2 = t >> 4;
        if (m < 15) {
            #pragma unroll
            for (int half = 0; half < 2; half++) {
                int r = r2 + half * 32;
                int gr = rowBase + r;
                if (gr < n) {
                    float sA = b1a[m], sB = b1b[m];
                    const uint2* hp = (const uint2*)&hh[(size_t)gr * DIM];
                    #pragma unroll 4
                    for (int kq = 0; kq < 16; kq++) {
                        float4 hv = unpackh4(hp[kq]);
                        float4 av = unpackh4(*(const uint2*)&xa_s[r][kq * 4]);
                        float4 wA = unpackh4(*(const uint2*)&p1t_s[0][m][kq * 4]);
                        float4 wB = unpackh4(*(const uint2*)&p1t_s[1][m][kq * 4]);
                        sA = fmaf(hv.x, wA.x, sA); sA = fmaf(hv.y, wA.y, sA);
                        sA = fmaf(hv.z, wA.z, sA); sA = fmaf(hv.w, wA.w, sA);
                        sB = fmaf(av.x, wB.x, sB); sB = fmaf(av.y, wB.y, sB);
                        sB = fmaf(av.z, wB.z, sB); sB = fmaf(av.w, wB.w, sB);
                    }
                    m_s[0][r][m] = fmaxf(sA, 0.f);
                    m_s[1][r][m] = fmaxf(sB, 0.f);
                } else {
                    m_s[0][r][m] = 0.f;
                    m_s[1][r][m] = 0.f;
                }
            }
        }
    }
    __syncthreads();

    // ---- phase 2: 2 rows x 4 cols register tile ----
    int cg = t & 15, rg = t >> 4;
    int c0 = cg * 4;
    int r0 = rg, r1 = rg + 32;

    float4 s0 = *(const float4*)&bc[c0];
    float4 s1 = s0;
    #pragma unroll 4
    for (int kq = 0; kq < 16; kq++) {
        float4 w0 = unpackh4(*(const uint2*)&wc_s[kq * 4 + 0][c0]);
        float4 w1 = unpackh4(*(const uint2*)&wc_s[kq * 4 + 1][c0]);
        float4 w2 = unpackh4(*(const uint2*)&wc_s[kq * 4 + 2][c0]);
        float4 w3 = unpackh4(*(const uint2*)&wc_s[kq * 4 + 3][c0]);
        float4 a0 = unpackh4(*(const uint2*)&xa_s[r0][kq * 4]);
        float4 a1 = unpackh4(*(const uint2*)&xa_s[r1][kq * 4]);
        fma4(s0, w0, a0.x); fma4(s0, w1, a0.y); fma4(s0, w2, a0.z); fma4(s0, w3, a0.w);
        fma4(s1, w0, a1.x); fma4(s1, w1, a1.y); fma4(s1, w2, a1.z); fma4(s1, w3, a1.w);
    }

    float4 u0 = *(const float4*)&b2a[c0];
    float4 u1 = u0;
    float4 v0 = *(const float4*)&b2b[c0];
    float4 v1 = v0;
    #pragma unroll 5
    for (int m = 0; m < BOT; m++) {
        float4 wa = unpackh4(*(const uint2*)&p2_s[0][m][c0]);
        float4 wb = unpackh4(*(const uint2*)&p2_s[1][m][c0]);
        float a0 = m_s[0][r0][m], a1 = m_s[0][r1][m];
        float b0 = m_s[1][r0][m], b1 = m_s[1][r1][m];
        fma4(u0, wa, a0); fma4(u1, wa, a1);
        fma4(v0, wb, b0); fma4(v1, wb, b1);
    }

    float4 sy = {0,0,0,0}, sy2 = {0,0,0,0};
    float4 su = {0,0,0,0}, su2 = {0,0,0,0};
    float4 sv = {0,0,0,0}, sv2 = {0,0,0,0};
    {
        int gr = rowBase + r0;
        if (gr < n) {
            size_t o = (size_t)gr * DIM + c0;
            *(uint2*)&yh[o] = packh4(s0);
            *(uint2*)&uh[o] = packh4(u0);
            *(uint2*)&vh[o] = packh4(v0);
            add4(sy, s0); fma4sq(sy2, s0);
            add4(su, u0); fma4sq(su2, u0);
            add4(sv, v0); fma4sq(sv2, v0);
        }
        gr = rowBase + r1;
        if (gr < n) {
            size_t o = (size_t)gr * DIM + c0;
            *(uint2*)&yh[o] = packh4(s1);
            *(uint2*)&uh[o] = packh4(u1);
            *(uint2*)&vh[o] = packh4(v1);
            add4(sy, s1); fma4sq(sy2, s1);
            add4(su, u1); fma4sq(su2, u1);
            add4(sv, v1); fma4sq(sv2, v1);
        }
    }

    wavered4(sy); wavered4(sy2);
    wavered4(su); wavered4(su2);
    wavered4(sv); wavered4(sv2);

    int wv = t >> 6, lane = t & 63;
    if (lane < 16) {
        *(float4*)&red_s[0][wv][c0] = sy;
        *(float4*)&red_s[1][wv][c0] = sy2;
        *(float4*)&red_s[2][wv][c0] = su;
        *(float4*)&red_s[3][wv][c0] = su2;
        *(float4*)&red_s[4][wv][c0] = sv;
        *(float4*)&red_s[5][wv][c0] = sv2;
    }
    __syncthreads();
    if (t < DIM) {
        float* gs = gsum + (size_t)(blockIdx.x & (NSTRIPE - 1)) * 6 * DIM;
        #pragma unroll
        for (int j = 0; j < 6; j++) {
            float v = red_s[j][0][t] + red_s[j][1][t] + red_s[j][2][t] + red_s[j][3][t]
                    + red_s[j][4][t] + red_s[j][5][t] + red_s[j][6][t] + red_s[j][7][t];
            atomicAdd(&gs[j * DIM + t], v);
        }
    }
}

// ---------------- apply: BN fold prologue + streaming body ----------------
// LAST=0: mid layer — relu, write fp16 hh. LAST=1: write f32 d_out.

template <int LAST>
__global__ __launch_bounds__(256) void apply_k(
    const __half* __restrict__ yh, const __half* __restrict__ uh,
    const __half* __restrict__ vh, const float* __restrict__ gsum,
    const float* __restrict__ bn_g, const float* __restrict__ bn_b,
    const float* __restrict__ pg0, const float* __restrict__ pb0,
    const float* __restrict__ pg1, const float* __restrict__ pb1,
    const float* __restrict__ gating, int l, int n,
    float* __restrict__ out, __half* __restrict__ hh, int n4) {
    __shared__ float STs[6][64];
    int t = threadIdx.x;
    if (t < 192) {
        int stat = t >> 6, c = t & 63;
        float s1 = 0.f, s2 = 0.f;
        #pragma unroll
        for (int k = 0; k < NSTRIPE; k++) {
            const float* gs = gsum + (size_t)k * 6 * DIM;
            s1 += gs[(2 * stat) * DIM + c];
            s2 += gs[(2 * stat + 1) * DIM + c];
        }
        float mean = s1 / (float)n;
        float var = s2 / (float)n - mean * mean;
        float rstd = rsqrtf(fmaxf(var, 0.f) + BN_EPS);
        float g, bb, gate;
        if (stat == 0)      { g = bn_g[c]; bb = bn_b[c]; gate = 1.f; }
        else if (stat == 1) { g = pg0[c];  bb = pb0[c];  gate = gating[0 * NLAYERS + l]; }
        else                { g = pg1[c];  bb = pb1[c];  gate = gating[1 * NLAYERS + l]; }
        STs[2 * stat][c] = g * rstd * gate;
        STs[2 * stat + 1][c] = (bb - mean * g * rstd) * gate;
    }
    __syncthreads();
    int i = blockIdx.x * blockDim.x + t;
    if (i >= n4) return;
    int c4 = (i & 15) * 4;
    float4 S0 = *(const float4*)&STs[0][c4];
    float4 T0 = *(const float4*)&STs[1][c4];
    float4 S1 = *(const float4*)&STs[2][c4];
    float4 T1 = *(const float4*)&STs[3][c4];
    float4 S2 = *(const float4*)&STs[4][c4];
    float4 T2 = *(const float4*)&STs[5][c4];
    float4 y = unpackh4(*(const uint2*)&yh[(size_t)i * 4]);
    float4 u = unpackh4(*(const uint2*)&uh[(size_t)i * 4]);
    float4 v = unpackh4(*(const uint2*)&vh[(size_t)i * 4]);
    float4 r;
    r.x = fmaf(y.x, S0.x, T0.x) + fmaf(u.x, S1.x, T1.x) + fmaf(v.x, S2.x, T2.x);
    r.y = fmaf(y.y, S0.y, T0.y) + fmaf(u.y, S1.y, T1.y) + fmaf(v.y, S2.y, T2.y);
    r.z = fmaf(y.z, S0.z, T0.z) + fmaf(u.z, S1.z, T1.z) + fmaf(v.z, S2.z, T2.z);
    r.w = fmaf(y.w, S0.w, T0.w) + fmaf(u.w, S1.w, T1.w) + fmaf(v.w, S2.w, T2.w);
    if (!LAST) {
        r.x = fmaxf(r.x, 0.f); r.y = fmaxf(r.y, 0.f);
        r.z = fmaxf(r.z, 0.f); r.w = fmaxf(r.w, 0.f);
        *(uint2*)&hh[(size_t)i * 4] = packh4(r);
    } else {
        *(float4*)&out[(size_t)i * 4] = r;
    }
}

// ---------------- fallback per-layer compute (small-ws path) ----------------

template <int MODE>  // 0: stats, 1: apply, 2: apply+relu
__global__ __launch_bounds__(256) void layer_k(
    const float* __restrict__ h, const float* __restrict__ aggr,
    const float* __restrict__ Wc, const float* __restrict__ bc,
    const float* __restrict__ p1a, const float* __restrict__ b1a,
    const float* __restrict__ p2a, const float* __restrict__ b2a,
    const float* __restrict__ p1b, const float* __restrict__ b1b,
    const float* __restrict__ p2b, const float* __restrict__ b2b,
    float* __restrict__ partials, const float* __restrict__ ST,
    float* __restrict__ hout, int n) {
    __shared__ float xh[ROWS_FB][DIM + 1];
    __shared__ float xa[ROWS_FB][DIM + 1];
    __shared__ float m0[ROWS_FB][17];
    __shared__ float m1[ROWS_FB][17];
    __shared__ float red[6][4][DIM];

    int t = threadIdx.x;
    int rowBase = blockIdx.x * ROWS_FB;

    #pragma unroll
    for (int i = 0; i < (ROWS_FB * DIM) / 256; i++) {
        int idx = t + i * 256;
        int r = idx >> 6, c = idx & 63;
        int gr = rowBase + r;
        float vh2 = 0.f, va = 0.f;
        if (gr < n) { vh2 = h[(size_t)gr * DIM + c]; va = aggr[(size_t)gr * DIM + c]; }
        xh[r][c] = vh2;
        xa[r][c] = va;
    }
    __syncthreads();

    {
        int r = t >> 3, sub = t & 7;
        #pragma unroll
        for (int half = 0; half < 2; half++) {
            int m = sub + half * 8;
            if (m < BOT) {
                float s0 = b1a[m], s1 = b1b[m];
                #pragma unroll
                for (int k = 0; k < DIM; k++) {
                    s0 = fmaf(xh[r][k], p1a[k * BOT + m], s0);
                    s1 = fmaf(xa[r][k], p1b[k * BOT + m], s1);
                }
                m0[r][m] = fmaxf(s0, 0.f);
                m1[r][m] = fmaxf(s1, 0.f);
            }
        }
    }
    __syncthreads();

    int col = t & 63;
    int rg = t >> 6;
    float sums[6] = {0.f, 0.f, 0.f, 0.f, 0.f, 0.f};
    float S0 = 0, T0 = 0, S1 = 0, T1 = 0, S2 = 0, T2 = 0;
    if (MODE != 0) {
        S0 = ST[col];        T0 = ST[64 + col];
        S1 = ST[128 + col];  T1 = ST[192 + col];
        S2 = ST[256 + col];  T2 = ST[320 + col];
    }
    #pragma unroll
    for (int i = 0; i < ROWS_FB / 4; i++) {
        int r = rg + i * 4;
        int gr = rowBase + r;
        float s = bc[col];
        #pragma unroll
        for (int k = 0; k < DIM; k++) s = fmaf(xa[r][k], Wc[k * DIM + col], s);
        float u = b2a[col];
        #pragma unroll
        for (int m = 0; m < BOT; m++) u = fmaf(m0[r][m], p2a[m * DIM + col], u);
        float v = b2b[col];
        #pragma unroll
        for (int m = 0; m < BOT; m++) v = fmaf(m1[r][m], p2b[m * DIM + col], v);
        if (MODE == 0) {
            if (gr < n) {
                sums[0] += s; sums[1] += s * s;
                sums[2] += u; sums[3] += u * u;
                sums[4] += v; sums[5] += v * v;
            }
        } else {
            float r0 = fmaf(s, S0, T0) + fmaf(u, S1, T1) + fmaf(v, S2, T2);
            if (MODE == 2) r0 = fmaxf(r0, 0.f);
            if (gr < n) hout[(size_t)gr * DIM + col] = r0;
        }
    }

    if (MODE == 0) {
        #pragma unroll
        for (int j = 0; j < 6; j++) red[j][rg][col] = sums[j];
        __syncthreads();
        if (t < DIM) {
            #pragma unroll
            for (int j = 0; j < 6; j++) {
                float v = red[j][0][t] + red[j][1][t] + red[j][2][t] + red[j][3][t];
                partials[((size_t)blockIdx.x * 6 + j) * DIM + t] = v;
            }
        }
    }
}

// ---------------- fallback stats reduce + BN fold ----------------

__global__ __launch_bounds__(256) void reduce_fold_k(
    const float* __restrict__ partials, int nb, int n,
    const float* __restrict__ bn_g, const float* __restrict__ bn_b,
    const float* __restrict__ pg0, const float* __restrict__ pb0,
    const float* __restrict__ pg1, const float* __restrict__ pb1,
    const float* __restrict__ gating, int l, float* __restrict__ ST) {
    __shared__ double red[6][256];
    int col = blockIdx.x;
    int t = threadIdx.x;
    double acc[6] = {0, 0, 0, 0, 0, 0};
    for (int b = t; b < nb; b += 256) {
        const float* p = partials + (size_t)b * 6 * DIM + col;
        #pragma unroll
        for (int j = 0; j < 6; j++) acc[j] += (double)p[j * DIM];
    }
    #pragma unroll
    for (int j = 0; j < 6; j++) red[j][t] = acc[j];
    __syncthreads();
    for (int off = 128; off > 0; off >>= 1) {
        if (t < off) {
            #pragma unroll
            for (int j = 0; j < 6; j++) red[j][t] += red[j][t + off];
        }
        __syncthreads();
    }
    if (t < 3) {
        int stat = t;
        float mean = (float)(red[2 * stat][0] / (double)n);
        float var = (float)(red[2 * stat + 1][0] / (double)n) - mean * mean;
        float rstd = rsqrtf(fmaxf(var, 0.f) + BN_EPS);
        float g, bb, gate;
        if (stat == 0)      { g = bn_g[col]; bb = bn_b[col]; gate = 1.f; }
        else if (stat == 1) { g = pg0[col];  bb = pb0[col];  gate = gating[0 * NLAYERS + l]; }
        else                { g = pg1[col];  bb = pb1[col];  gate = gating[1 * NLAYERS + l]; }
        float S = g * rstd * gate;
        float T = (bb - mean * g * rstd) * gate;
        ST[stat * 128 + col] = S;
        ST[stat * 128 + 64 + col] = T;
    }
}

// ---------------- host ----------------

static inline char* bump(char*& p, size_t bytes) {
    char* r = p;
    p += (bytes + 255) & ~(size_t)255;
    return r;
}

extern "C" void kernel_launch(void* const* d_in, const int* in_sizes, int n_in,
                              void* d_out, int out_size, void* d_ws, size_t ws_size,
                              hipStream_t stream) {
    const float* x      = (const float*)d_in[0];
    const int*   ei     = (const int*)d_in[1];
    const float* W      = (const float*)d_in[2];
    const float* bconv  = (const float*)d_in[3];
    const float* bn_g   = (const float*)d_in[4];
    const float* bn_b   = (const float*)d_in[5];
    const float* pw1    = (const float*)d_in[6];
    const float* pb1    = (const float*)d_in[7];
    const float* pw2    = (const float*)d_in[8];
    const float* pb2    = (const float*)d_in[9];
    const float* pbn_g  = (const float*)d_in[10];
    const float* pbn_b  = (const float*)d_in[11];
    const float* gating = (const float*)d_in[12];

    int n = in_sizes[0] / DIM;
    int E = in_sizes[1] / 2;
    int nbS  = (n + ROWS - 1) / ROWS;
    int nbFB = (n + ROWS_FB - 1) / ROWS_FB;
    int nb1024 = (n + 1023) / 1024;
    int nbkt = (n + 255) >> BKT_SHIFT;
    size_t n64b = (size_t)n * DIM * sizeof(float);
    size_t n64h = (size_t)n * DIM * sizeof(__half);
    int n4 = n * (DIM / 4);

    // carve workspace
    char* p = (char*)d_ws;
    float* h_ws     = (float*)bump(p, n64b);           // fallback only
    float* partials = (float*)bump(p, (size_t)nbFB * 6 * DIM * sizeof(float));
    float* ST       = (float*)bump(p, 6 * 128 * sizeof(float));
    float* gsum     = (float*)bump(p, (size_t)NLAYERS * NSTRIPE * 6 * DIM * sizeof(float));
    int*   bsum     = (int*)bump(p, (size_t)nb1024 * sizeof(int));
    int*   boff     = (int*)bump(p, (size_t)nb1024 * sizeof(int));
    int*   bcur     = (int*)bump(p, 257 * sizeof(int));
    int*   deg      = (int*)bump(p, (size_t)n * sizeof(int));
    int*   row_ptr  = (int*)bump(p, (size_t)(n + 1) * sizeof(int));
    int*   csr      = (int*)bump(p, (size_t)E * sizeof(int));
    float* aggr_f   = (float*)bump(p, n64b);   // fallback f32 aggr; fast path uses ah
    __half* ah = (__half*)bump(p, n64h);
    __half* yh = (__half*)bump(p, n64h);
    __half* uh = (__half*)bump(p, n64h);
    __half* vh = (__half*)bump(p, n64h);
    __half* hh = (__half*)bump(p, n64h);
    bool fast = ((size_t)(p - (char*)d_ws) <= ws_size);
    int2* part = (int2*)aggr_f;   // aliases fallback aggr; used only pre-loop

    const int* esrc = ei;
    const int* edst = ei + E;

    // CSR build + stats zero
    hipMemsetAsync(deg, 0, (size_t)n * sizeof(int), stream);
    hipMemsetAsync(gsum, 0, (size_t)NLAYERS * NSTRIPE * 6 * DIM * sizeof(float), stream);
    hist_k<<<(E + 255) / 256, 256, 0, stream>>>(edst, deg, E);
    scan_part_k<<<nb1024, 1024, 0, stream>>>(deg, row_ptr, bsum, n);
    scan_top_k<<<1, 1024, 0, stream>>>(bsum, boff, nb1024, row_ptr, n);
    scan_add_k<<<(n + 255) / 256, 256, 0, stream>>>(row_ptr, boff, deg, bcur, n);
    if (fast) {
        part_k<<<(E + 2047) / 2048, 256, 0, stream>>>(esrc, edst, bcur, part, E);
        bscat_k<<<nbkt, 256, 0, stream>>>(part, row_ptr, deg, csr, n);
        tohalf_k<<<(n4 + 255) / 256, 256, 0, stream>>>(x, hh, n4);
    } else {
        scatter_k<<<(E + 255) / 256, 256, 0, stream>>>(esrc, edst, deg, csr, E);
    }

    for (int l = 0; l < NLAYERS; l++) {
        const float* Wl  = W     + (size_t)l * DIM * DIM;
        const float* bl  = bconv + (size_t)l * DIM;
        const float* bgl = bn_g  + (size_t)l * DIM;
        const float* bbl = bn_b  + (size_t)l * DIM;
        const float* p1a = pw1 + ((size_t)0 * NLAYERS + l) * DIM * BOT;
        const float* p1b = pw1 + ((size_t)1 * NLAYERS + l) * DIM * BOT;
        const float* b1a = pb1 + ((size_t)0 * NLAYERS + l) * BOT;
        const float* b1b = pb1 + ((size_t)1 * NLAYERS + l) * BOT;
        const float* p2a = pw2 + ((size_t)0 * NLAYERS + l) * BOT * DIM;
        const float* p2b = pw2 + ((size_t)1 * NLAYERS + l) * BOT * DIM;
        const float* b2a = pb2 + ((size_t)0 * NLAYERS + l) * DIM;
        const float* b2b = pb2 + ((size_t)1 * NLAYERS + l) * DIM;
        const float* g0  = pbn_g + ((size_t)0 * NLAYERS + l) * DIM;
        const float* g1  = pbn_g + ((size_t)1 * NLAYERS + l) * DIM;
        const float* be0 = pbn_b + ((size_t)0 * NLAYERS + l) * DIM;
        const float* be1 = pbn_b + ((size_t)1 * NLAYERS + l) * DIM;

        float* gsl = gsum + (size_t)l * NSTRIPE * 6 * DIM;

        if (fast) {
            aggr_h_k<<<(n + 3) / 4, 256, 0, stream>>>(hh, row_ptr, csr, ah, n);

            stats_k<<<nbS, 512, 0, stream>>>(
                hh, ah, Wl, bl, p1a, b1a, p2a, b2a,
                p1b, b1b, p2b, b2b, gsl, yh, uh, vh, n);

            if (l < NLAYERS - 1)
                apply_k<0><<<(n4 + 255) / 256, 256, 0, stream>>>(
                    yh, uh, vh, gsl, bgl, bbl, g0, be0, g1, be1, gating, l, n,
                    nullptr, hh, n4);
            else
                apply_k<1><<<(n4 + 255) / 256, 256, 0, stream>>>(
                    yh, uh, vh, gsl, bgl, bbl, g0, be0, g1, be1, gating, l, n,
                    (float*)d_out, hh, n4);
        } else {
            const float* hin = (l == 0) ? x : h_ws;

            aggr_k<<<(n + 3) / 4, 256, 0, stream>>>(hin, row_ptr, csr, aggr_f, n);

            layer_k<0><<<nbFB, 256, 0, stream>>>(
                hin, aggr_f, Wl, bl, p1a, b1a, p2a, b2a, p1b, b1b, p2b, b2b,
                partials, nullptr, nullptr, n);

            reduce_fold_k<<<DIM, 256, 0, stream>>>(partials, nbFB, n, bgl, bbl,
                                                   g0, be0, g1, be1, gating, l, ST);

            if (l < NLAYERS - 1) {
                layer_k<2><<<nbFB, 256, 0, stream>>>(
                    hin, aggr_f, Wl, bl, p1a, b1a, p2a, b2a, p1b, b1b, p2b, b2b,
                    nullptr, ST, h_ws, n);
            } else {
                layer_k<1><<<nbFB, 256, 0, stream>>>(
                    hin, aggr_f, Wl, bl, p1a, b1a, p2a, b2a, p1b, b1b, p2b, b2b,
                    nullptr, ST, (float*)d_out, n);
            }
        }
    }
}

// Round 18
// 400.991 us; speedup vs baseline: 1.0914x; 1.0914x over previous
//
#include <hip/hip_runtime.h>
#include <hip/hip_fp16.h>

#define DIM 64
#define BOT 15
#define NLAYERS 5
#define BN_EPS 1e-5f
#define ROWS 64            // stats_k rows per block (512 threads)
#define ROWS_FB 32         // fallback layer_k rows per block
#define BKT_SHIFT 8        // bucket = dst >> 8
#define NSTRIPE 4          // gsum contention stripes

__device__ inline void fma4(float4& acc, const float4& a, float s) {
    acc.x = fmaf(a.x, s, acc.x); acc.y = fmaf(a.y, s, acc.y);
    acc.z = fmaf(a.z, s, acc.z); acc.w = fmaf(a.w, s, acc.w);
}
__device__ inline void add4(float4& acc, const float4& a) {
    acc.x += a.x; acc.y += a.y; acc.z += a.z; acc.w += a.w;
}
__device__ inline void fma4sq(float4& acc, const float4& a) {
    acc.x = fmaf(a.x, a.x, acc.x); acc.y = fmaf(a.y, a.y, acc.y);
    acc.z = fmaf(a.z, a.z, acc.z); acc.w = fmaf(a.w, a.w, acc.w);
}
__device__ inline void wavered4(float4& v) {
    v.x += __shfl_xor(v.x, 16); v.y += __shfl_xor(v.y, 16);
    v.z += __shfl_xor(v.z, 16); v.w += __shfl_xor(v.w, 16);
    v.x += __shfl_xor(v.x, 32); v.y += __shfl_xor(v.y, 32);
    v.z += __shfl_xor(v.z, 32); v.w += __shfl_xor(v.w, 32);
}
__device__ inline uint2 packh4(const float4& v) {
    __half2 a = __floats2half2_rn(v.x, v.y);
    __half2 b = __floats2half2_rn(v.z, v.w);
    uint2 pk;
    pk.x = *(unsigned int*)&a;
    pk.y = *(unsigned int*)&b;
    return pk;
}
__device__ inline float4 unpackh4(uint2 pk) {
    __half2 a = *(__half2*)&pk.x;
    __half2 b = *(__half2*)&pk.y;
    float4 v;
    v.x = __low2float(a); v.y = __high2float(a);
    v.z = __low2float(b); v.w = __high2float(b);
    return v;
}

// ---------------- CSR build ----------------

__global__ __launch_bounds__(256) void hist_k(const int* __restrict__ dst,
                                              int* __restrict__ deg, int E) {
    int e = blockIdx.x * blockDim.x + threadIdx.x;
    if (e < E) atomicAdd(&deg[dst[e]], 1);
}

__global__ __launch_bounds__(1024) void scan_part_k(const int* __restrict__ deg,
                                                    int* __restrict__ excl,
                                                    int* __restrict__ bsum, int n) {
    __shared__ int buf[1024];
    int t = threadIdx.x;
    int idx = blockIdx.x * 1024 + t;
    int v = (idx < n) ? deg[idx] : 0;
    buf[t] = v;
    __syncthreads();
    for (int off = 1; off < 1024; off <<= 1) {
        int x = (t >= off) ? buf[t - off] : 0;
        __syncthreads();
        buf[t] += x;
        __syncthreads();
    }
    if (idx < n) excl[idx] = buf[t] - v;
    if (t == 0) bsum[blockIdx.x] = buf[1023];
}

__global__ __launch_bounds__(1024) void scan_top_k(const int* __restrict__ bsum,
                                                   int* __restrict__ boff, int nb,
                                                   int* __restrict__ row_ptr, int n) {
    __shared__ int buf[1024];
    int t = threadIdx.x;
    int v = (t < nb) ? bsum[t] : 0;
    buf[t] = v;
    __syncthreads();
    for (int off = 1; off < 1024; off <<= 1) {
        int x = (t >= off) ? buf[t - off] : 0;
        __syncthreads();
        buf[t] += x;
        __syncthreads();
    }
    if (t < nb) boff[t] = buf[t] - v;
    if (t == 1023) row_ptr[n] = buf[1023];
}

__global__ __launch_bounds__(256) void scan_add_k(int* __restrict__ row_ptr,
                                                  const int* __restrict__ boff,
                                                  int* __restrict__ deg,
                                                  int* __restrict__ bcur, int n) {
    int i = blockIdx.x * blockDim.x + threadIdx.x;
    if (i < n) {
        int v = row_ptr[i] + boff[i >> 10];
        row_ptr[i] = v;
        deg[i] = v;
        if ((i & 255) == 0) bcur[i >> BKT_SHIFT] = v;
    }
}

// fallback flat scatter (small-ws path)
__global__ __launch_bounds__(256) void scatter_k(const int* __restrict__ src,
                                                 const int* __restrict__ dst,
                                                 int* __restrict__ cursor,
                                                 int* __restrict__ csr, int E) {
    int e = blockIdx.x * blockDim.x + threadIdx.x;
    if (e < E) {
        int p = atomicAdd(&cursor[dst[e]], 1);
        csr[p] = src[e];
    }
}

// phase A: LDS-binned partition of edges into dst-buckets
__global__ __launch_bounds__(256) void part_k(const int* __restrict__ src,
                                              const int* __restrict__ dst,
                                              int* __restrict__ bcur,
                                              int2* __restrict__ part, int E) {
    __shared__ int hist[256];
    __shared__ int cur[256];
    int t = threadIdx.x;
    int base = blockIdx.x * 2048;
    hist[t] = 0;
    __syncthreads();
    int2 ed[8];
    int bk[8];
    #pragma unroll
    for (int k = 0; k < 8; k++) {
        int i = base + k * 256 + t;
        if (i < E) {
            ed[k].x = src[i];
            ed[k].y = dst[i];
            bk[k] = ed[k].y >> BKT_SHIFT;
            atomicAdd(&hist[bk[k]], 1);
        } else bk[k] = -1;
    }
    __syncthreads();
    int h = hist[t];
    if (h > 0) cur[t] = atomicAdd(&bcur[t], h);
    __syncthreads();
    #pragma unroll
    for (int k = 0; k < 8; k++) {
        if (bk[k] >= 0) {
            int p = atomicAdd(&cur[bk[k]], 1);
            part[p] = ed[k];
        }
    }
}

// phase B: one block per bucket
__global__ __launch_bounds__(256) void bscat_k(const int2* __restrict__ part,
                                               const int* __restrict__ row_ptr,
                                               int* __restrict__ cursor,
                                               int* __restrict__ csr, int n) {
    int b = blockIdx.x;
    int lo = row_ptr[b << BKT_SHIFT];
    int hiN = (b + 1) << BKT_SHIFT;
    int hi = row_ptr[hiN < n ? hiN : n];
    for (int i = lo + (int)threadIdx.x; i < hi; i += 256) {
        int2 e = part[i];
        int p = atomicAdd(&cursor[e.y], 1);
        csr[p] = e.x;
    }
}

// ---------------- f32 -> fp16 mirror ----------------

__global__ __launch_bounds__(256) void tohalf_k(const float* __restrict__ x,
                                                __half* __restrict__ hh, int n4) {
    int i = blockIdx.x * blockDim.x + threadIdx.x;
    if (i >= n4) return;
    float4 v = *(const float4*)&x[(size_t)i * 4];
    *(uint2*)&hh[(size_t)i * 4] = packh4(v);
}

// ---------------- aggregation (fp16 gather, fp16 store) ----------------

__global__ __launch_bounds__(256) void aggr_h_k(const __half* __restrict__ hh,
                                                const int* __restrict__ row_ptr,
                                                const int* __restrict__ csr,
                                                __half* __restrict__ ah, int n) {
    int gid = blockIdx.x * blockDim.x + threadIdx.x;
    int node = gid >> 6;
    int lane = threadIdx.x & 63;
    if (node >= n) return;
    int j = lane >> 3, q = lane & 7;
    int s = row_ptr[node], e = row_ptr[node + 1];
    float acc[8] = {0.f, 0.f, 0.f, 0.f, 0.f, 0.f, 0.f, 0.f};
    #pragma unroll 2
    for (int i = s; i < e; i += 8) {
        int ii = i + j;
        if (ii < e) {
            int idx = csr[ii];
            uint4 raw = *(const uint4*)&hh[(size_t)idx * DIM + q * 8];
            const __half2* hp = (const __half2*)&raw;
            #pragma unroll
            for (int k = 0; k < 4; k++) {
                acc[2 * k]     += __low2float(hp[k]);
                acc[2 * k + 1] += __high2float(hp[k]);
            }
        }
    }
    #pragma unroll
    for (int off = 8; off <= 32; off <<= 1) {
        #pragma unroll
        for (int k = 0; k < 8; k++) acc[k] += __shfl_xor(acc[k], off);
    }
    if (lane < 8) {
        float4 a = {acc[0], acc[1], acc[2], acc[3]};
        float4 b = {acc[4], acc[5], acc[6], acc[7]};
        uint2 pa = packh4(a), pb = packh4(b);
        uint4 pk = {pa.x, pa.y, pb.x, pb.y};
        *(uint4*)&ah[(size_t)node * DIM + q * 8] = pk;
    }
}

// fallback f32 gather
__global__ __launch_bounds__(256) void aggr_k(const float* __restrict__ h,
                                              const int* __restrict__ row_ptr,
                                              const int* __restrict__ csr,
                                              float* __restrict__ out, int n) {
    int gid = blockIdx.x * blockDim.x + threadIdx.x;
    int node = gid >> 6;
    int lane = threadIdx.x & 63;
    if (node >= n) return;
    int j = lane >> 4, q = lane & 15;
    int s = row_ptr[node], e = row_ptr[node + 1];
    float4 acc = {0.f, 0.f, 0.f, 0.f};
    #pragma unroll 4
    for (int i = s; i < e; i += 4) {
        int ii = i + j;
        if (ii < e) {
            int idx = csr[ii];
            float4 v = *(const float4*)&h[(size_t)idx * DIM + q * 4];
            add4(acc, v);
        }
    }
    wavered4(acc);
    if (lane < 16) *(float4*)&out[(size_t)node * DIM + q * 4] = acc;
}

// ---------------- stats pass (round-16 champion): f32 LDS, fp16 global streams --
// launch_bounds(512,4): VGPR <= 128. r17's (512,6) squeezed VGPR to 40 and
// doubled the instruction count — 96-128 regs is this kernel's sweet spot.

__global__ __launch_bounds__(512, 4) void stats_k(
    const __half* __restrict__ hh, const __half* __restrict__ ah,
    const float* __restrict__ Wc, const float* __restrict__ bc,
    const float* __restrict__ p1a, const float* __restrict__ b1a,
    const float* __restrict__ p2a, const float* __restrict__ b2a,
    const float* __restrict__ p1b, const float* __restrict__ b1b,
    const float* __restrict__ p2b, const float* __restrict__ b2b,
    float* __restrict__ gsum,          // [NSTRIPE][6][64], pre-zeroed
    __half* __restrict__ yh, __half* __restrict__ uh, __half* __restrict__ vh,
    int n) {
    __shared__ float xa_s[ROWS][68];
    __shared__ float wc_s[64][64];
    __shared__ float p1t_s[2][15][68];
    __shared__ float p2_s[2][15][64];
    __shared__ float m_s[2][ROWS][17];
    __shared__ float red_s[6][8][64];

    int t = threadIdx.x;
    int rowBase = blockIdx.x * ROWS;

    #pragma unroll
    for (int i = 0; i < 2; i++) {
        int idx = t + i * 512;
        int r = idx >> 4, c4 = (idx & 15) * 4;
        int gr = rowBase + r;
        float4 va = {0.f, 0.f, 0.f, 0.f};
        if (gr < n) va = unpackh4(*(const uint2*)&ah[(size_t)gr * DIM + c4]);
        *(float4*)&xa_s[r][c4] = va;
    }
    #pragma unroll
    for (int i = 0; i < 2; i++) {
        int idx = t + i * 512;
        int k = idx >> 4, c4 = (idx & 15) * 4;
        *(float4*)&wc_s[k][c4] = *(const float4*)&Wc[k * DIM + c4];
    }
    if (t < 240) {
        int m = t >> 4, c4 = (t & 15) * 4;
        *(float4*)&p2_s[0][m][c4] = *(const float4*)&p2a[m * DIM + c4];
        *(float4*)&p2_s[1][m][c4] = *(const float4*)&p2b[m * DIM + c4];
    }
    #pragma unroll
    for (int i = 0; i < 2; i++) {
        int idx = t + i * 512;
        if (idx < 960) {
            int k = idx / 15, m = idx % 15;
            p1t_s[0][m][k] = p1a[idx];
            p1t_s[1][m][k] = p1b[idx];
        }
    }
    __syncthreads();

    // phase 1: bottleneck mids; h read from fp16 mirror (gated path)
    {
        int m = t & 15, r2 = t >> 4;
        if (m < 15) {
            #pragma unroll
            for (int half = 0; half < 2; half++) {
                int r = r2 + half * 32;
                int gr = rowBase + r;
                if (gr < n) {
                    float sA = b1a[m], sB = b1b[m];
                    const uint2* hp = (const uint2*)&hh[(size_t)gr * DIM];
                    #pragma unroll 4
                    for (int kq = 0; kq < 16; kq++) {
                        float4 hv = unpackh4(hp[kq]);
                        float4 av = *(const float4*)&xa_s[r][kq * 4];
                        float4 wA = *(const float4*)&p1t_s[0][m][kq * 4];
                        float4 wB = *(const float4*)&p1t_s[1][m][kq * 4];
                        sA = fmaf(hv.x, wA.x, sA); sA = fmaf(hv.y, wA.y, sA);
                        sA = fmaf(hv.z, wA.z, sA); sA = fmaf(hv.w, wA.w, sA);
                        sB = fmaf(av.x, wB.x, sB); sB = fmaf(av.y, wB.y, sB);
                        sB = fmaf(av.z, wB.z, sB); sB = fmaf(av.w, wB.w, sB);
                    }
                    m_s[0][r][m] = fmaxf(sA, 0.f);
                    m_s[1][r][m] = fmaxf(sB, 0.f);
                } else {
                    m_s[0][r][m] = 0.f;
                    m_s[1][r][m] = 0.f;
                }
            }
        }
    }
    __syncthreads();

    int cg = t & 15, rg = t >> 4;
    int c0 = cg * 4;
    int r0 = rg, r1 = rg + 32;

    float4 s0 = *(const float4*)&bc[c0];
    float4 s1 = s0;
    #pragma unroll 4
    for (int kq = 0; kq < 16; kq++) {
        float4 w0 = *(const float4*)&wc_s[kq * 4 + 0][c0];
        float4 w1 = *(const float4*)&wc_s[kq * 4 + 1][c0];
        float4 w2 = *(const float4*)&wc_s[kq * 4 + 2][c0];
        float4 w3 = *(const float4*)&wc_s[kq * 4 + 3][c0];
        float4 a0 = *(const float4*)&xa_s[r0][kq * 4];
        float4 a1 = *(const float4*)&xa_s[r1][kq * 4];
        fma4(s0, w0, a0.x); fma4(s0, w1, a0.y); fma4(s0, w2, a0.z); fma4(s0, w3, a0.w);
        fma4(s1, w0, a1.x); fma4(s1, w1, a1.y); fma4(s1, w2, a1.z); fma4(s1, w3, a1.w);
    }

    float4 u0 = *(const float4*)&b2a[c0];
    float4 u1 = u0;
    float4 v0 = *(const float4*)&b2b[c0];
    float4 v1 = v0;
    #pragma unroll 5
    for (int m = 0; m < BOT; m++) {
        float4 wa = *(const float4*)&p2_s[0][m][c0];
        float4 wb = *(const float4*)&p2_s[1][m][c0];
        float a0 = m_s[0][r0][m], a1 = m_s[0][r1][m];
        float b0 = m_s[1][r0][m], b1 = m_s[1][r1][m];
        fma4(u0, wa, a0); fma4(u1, wa, a1);
        fma4(v0, wb, b0); fma4(v1, wb, b1);
    }

    float4 sy = {0,0,0,0}, sy2 = {0,0,0,0};
    float4 su = {0,0,0,0}, su2 = {0,0,0,0};
    float4 sv = {0,0,0,0}, sv2 = {0,0,0,0};
    {
        int gr = rowBase + r0;
        if (gr < n) {
            size_t o = (size_t)gr * DIM + c0;
            *(uint2*)&yh[o] = packh4(s0);
            *(uint2*)&uh[o] = packh4(u0);
            *(uint2*)&vh[o] = packh4(v0);
            add4(sy, s0); fma4sq(sy2, s0);
            add4(su, u0); fma4sq(su2, u0);
            add4(sv, v0); fma4sq(sv2, v0);
        }
        gr = rowBase + r1;
        if (gr < n) {
            size_t o = (size_t)gr * DIM + c0;
            *(uint2*)&yh[o] = packh4(s1);
            *(uint2*)&uh[o] = packh4(u1);
            *(uint2*)&vh[o] = packh4(v1);
            add4(sy, s1); fma4sq(sy2, s1);
            add4(su, u1); fma4sq(su2, u1);
            add4(sv, v1); fma4sq(sv2, v1);
        }
    }

    wavered4(sy); wavered4(sy2);
    wavered4(su); wavered4(su2);
    wavered4(sv); wavered4(sv2);

    int wv = t >> 6, lane = t & 63;
    if (lane < 16) {
        *(float4*)&red_s[0][wv][c0] = sy;
        *(float4*)&red_s[1][wv][c0] = sy2;
        *(float4*)&red_s[2][wv][c0] = su;
        *(float4*)&red_s[3][wv][c0] = su2;
        *(float4*)&red_s[4][wv][c0] = sv;
        *(float4*)&red_s[5][wv][c0] = sv2;
    }
    __syncthreads();
    if (t < DIM) {
        float* gs = gsum + (size_t)(blockIdx.x & (NSTRIPE - 1)) * 6 * DIM;
        #pragma unroll
        for (int j = 0; j < 6; j++) {
            float v = red_s[j][0][t] + red_s[j][1][t] + red_s[j][2][t] + red_s[j][3][t]
                    + red_s[j][4][t] + red_s[j][5][t] + red_s[j][6][t] + red_s[j][7][t];
            atomicAdd(&gs[j * DIM + t], v);
        }
    }
}

// ---------------- apply: BN fold prologue + streaming body ----------------
// LAST=0: mid layer — relu, write fp16 hh. LAST=1: write f32 d_out.

template <int LAST>
__global__ __launch_bounds__(256) void apply_k(
    const __half* __restrict__ yh, const __half* __restrict__ uh,
    const __half* __restrict__ vh, const float* __restrict__ gsum,
    const float* __restrict__ bn_g, const float* __restrict__ bn_b,
    const float* __restrict__ pg0, const float* __restrict__ pb0,
    const float* __restrict__ pg1, const float* __restrict__ pb1,
    const float* __restrict__ gating, int l, int n,
    float* __restrict__ out, __half* __restrict__ hh, int n4) {
    __shared__ float STs[6][64];
    int t = threadIdx.x;
    if (t < 192) {
        int stat = t >> 6, c = t & 63;
        float s1 = 0.f, s2 = 0.f;
        #pragma unroll
        for (int k = 0; k < NSTRIPE; k++) {
            const float* gs = gsum + (size_t)k * 6 * DIM;
            s1 += gs[(2 * stat) * DIM + c];
            s2 += gs[(2 * stat + 1) * DIM + c];
        }
        float mean = s1 / (float)n;
        float var = s2 / (float)n - mean * mean;
        float rstd = rsqrtf(fmaxf(var, 0.f) + BN_EPS);
        float g, bb, gate;
        if (stat == 0)      { g = bn_g[c]; bb = bn_b[c]; gate = 1.f; }
        else if (stat == 1) { g = pg0[c];  bb = pb0[c];  gate = gating[0 * NLAYERS + l]; }
        else                { g = pg1[c];  bb = pb1[c];  gate = gating[1 * NLAYERS + l]; }
        STs[2 * stat][c] = g * rstd * gate;
        STs[2 * stat + 1][c] = (bb - mean * g * rstd) * gate;
    }
    __syncthreads();
    int i = blockIdx.x * blockDim.x + t;
    if (i >= n4) return;
    int c4 = (i & 15) * 4;
    float4 S0 = *(const float4*)&STs[0][c4];
    float4 T0 = *(const float4*)&STs[1][c4];
    float4 S1 = *(const float4*)&STs[2][c4];
    float4 T1 = *(const float4*)&STs[3][c4];
    float4 S2 = *(const float4*)&STs[4][c4];
    float4 T2 = *(const float4*)&STs[5][c4];
    float4 y = unpackh4(*(const uint2*)&yh[(size_t)i * 4]);
    float4 u = unpackh4(*(const uint2*)&uh[(size_t)i * 4]);
    float4 v = unpackh4(*(const uint2*)&vh[(size_t)i * 4]);
    float4 r;
    r.x = fmaf(y.x, S0.x, T0.x) + fmaf(u.x, S1.x, T1.x) + fmaf(v.x, S2.x, T2.x);
    r.y = fmaf(y.y, S0.y, T0.y) + fmaf(u.y, S1.y, T1.y) + fmaf(v.y, S2.y, T2.y);
    r.z = fmaf(y.z, S0.z, T0.z) + fmaf(u.z, S1.z, T1.z) + fmaf(v.z, S2.z, T2.z);
    r.w = fmaf(y.w, S0.w, T0.w) + fmaf(u.w, S1.w, T1.w) + fmaf(v.w, S2.w, T2.w);
    if (!LAST) {
        r.x = fmaxf(r.x, 0.f); r.y = fmaxf(r.y, 0.f);
        r.z = fmaxf(r.z, 0.f); r.w = fmaxf(r.w, 0.f);
        *(uint2*)&hh[(size_t)i * 4] = packh4(r);
    } else {
        *(float4*)&out[(size_t)i * 4] = r;
    }
}

// ---------------- fallback per-layer compute (small-ws path) ----------------

template <int MODE>  // 0: stats, 1: apply, 2: apply+relu
__global__ __launch_bounds__(256) void layer_k(
    const float* __restrict__ h, const float* __restrict__ aggr,
    const float* __restrict__ Wc, const float* __restrict__ bc,
    const float* __restrict__ p1a, const float* __restrict__ b1a,
    const float* __restrict__ p2a, const float* __restrict__ b2a,
    const float* __restrict__ p1b, const float* __restrict__ b1b,
    const float* __restrict__ p2b, const float* __restrict__ b2b,
    float* __restrict__ partials, const float* __restrict__ ST,
    float* __restrict__ hout, int n) {
    __shared__ float xh[ROWS_FB][DIM + 1];
    __shared__ float xa[ROWS_FB][DIM + 1];
    __shared__ float m0[ROWS_FB][17];
    __shared__ float m1[ROWS_FB][17];
    __shared__ float red[6][4][DIM];

    int t = threadIdx.x;
    int rowBase = blockIdx.x * ROWS_FB;

    #pragma unroll
    for (int i = 0; i < (ROWS_FB * DIM) / 256; i++) {
        int idx = t + i * 256;
        int r = idx >> 6, c = idx & 63;
        int gr = rowBase + r;
        float vh2 = 0.f, va = 0.f;
        if (gr < n) { vh2 = h[(size_t)gr * DIM + c]; va = aggr[(size_t)gr * DIM + c]; }
        xh[r][c] = vh2;
        xa[r][c] = va;
    }
    __syncthreads();

    {
        int r = t >> 3, sub = t & 7;
        #pragma unroll
        for (int half = 0; half < 2; half++) {
            int m = sub + half * 8;
            if (m < BOT) {
                float s0 = b1a[m], s1 = b1b[m];
                #pragma unroll
                for (int k = 0; k < DIM; k++) {
                    s0 = fmaf(xh[r][k], p1a[k * BOT + m], s0);
                    s1 = fmaf(xa[r][k], p1b[k * BOT + m], s1);
                }
                m0[r][m] = fmaxf(s0, 0.f);
                m1[r][m] = fmaxf(s1, 0.f);
            }
        }
    }
    __syncthreads();

    int col = t & 63;
    int rg = t >> 6;
    float sums[6] = {0.f, 0.f, 0.f, 0.f, 0.f, 0.f};
    float S0 = 0, T0 = 0, S1 = 0, T1 = 0, S2 = 0, T2 = 0;
    if (MODE != 0) {
        S0 = ST[col];        T0 = ST[64 + col];
        S1 = ST[128 + col];  T1 = ST[192 + col];
        S2 = ST[256 + col];  T2 = ST[320 + col];
    }
    #pragma unroll
    for (int i = 0; i < ROWS_FB / 4; i++) {
        int r = rg + i * 4;
        int gr = rowBase + r;
        float s = bc[col];
        #pragma unroll
        for (int k = 0; k < DIM; k++) s = fmaf(xa[r][k], Wc[k * DIM + col], s);
        float u = b2a[col];
        #pragma unroll
        for (int m = 0; m < BOT; m++) u = fmaf(m0[r][m], p2a[m * DIM + col], u);
        float v = b2b[col];
        #pragma unroll
        for (int m = 0; m < BOT; m++) v = fmaf(m1[r][m], p2b[m * DIM + col], v);
        if (MODE == 0) {
            if (gr < n) {
                sums[0] += s; sums[1] += s * s;
                sums[2] += u; sums[3] += u * u;
                sums[4] += v; sums[5] += v * v;
            }
        } else {
            float r0 = fmaf(s, S0, T0) + fmaf(u, S1, T1) + fmaf(v, S2, T2);
            if (MODE == 2) r0 = fmaxf(r0, 0.f);
            if (gr < n) hout[(size_t)gr * DIM + col] = r0;
        }
    }

    if (MODE == 0) {
        #pragma unroll
        for (int j = 0; j < 6; j++) red[j][rg][col] = sums[j];
        __syncthreads();
        if (t < DIM) {
            #pragma unroll
            for (int j = 0; j < 6; j++) {
                float v = red[j][0][t] + red[j][1][t] + red[j][2][t] + red[j][3][t];
                partials[((size_t)blockIdx.x * 6 + j) * DIM + t] = v;
            }
        }
    }
}

// ---------------- fallback stats reduce + BN fold ----------------

__global__ __launch_bounds__(256) void reduce_fold_k(
    const float* __restrict__ partials, int nb, int n,
    const float* __restrict__ bn_g, const float* __restrict__ bn_b,
    const float* __restrict__ pg0, const float* __restrict__ pb0,
    const float* __restrict__ pg1, const float* __restrict__ pb1,
    const float* __restrict__ gating, int l, float* __restrict__ ST) {
    __shared__ double red[6][256];
    int col = blockIdx.x;
    int t = threadIdx.x;
    double acc[6] = {0, 0, 0, 0, 0, 0};
    for (int b = t; b < nb; b += 256) {
        const float* p = partials + (size_t)b * 6 * DIM + col;
        #pragma unroll
        for (int j = 0; j < 6; j++) acc[j] += (double)p[j * DIM];
    }
    #pragma unroll
    for (int j = 0; j < 6; j++) red[j][t] = acc[j];
    __syncthreads();
    for (int off = 128; off > 0; off >>= 1) {
        if (t < off) {
            #pragma unroll
            for (int j = 0; j < 6; j++) red[j][t] += red[j][t + off];
        }
        __syncthreads();
    }
    if (t < 3) {
        int stat = t;
        float mean = (float)(red[2 * stat][0] / (double)n);
        float var = (float)(red[2 * stat + 1][0] / (double)n) - mean * mean;
        float rstd = rsqrtf(fmaxf(var, 0.f) + BN_EPS);
        float g, bb, gate;
        if (stat == 0)      { g = bn_g[col]; bb = bn_b[col]; gate = 1.f; }
        else if (stat == 1) { g = pg0[col];  bb = pb0[col];  gate = gating[0 * NLAYERS + l]; }
        else                { g = pg1[col];  bb = pb1[col];  gate = gating[1 * NLAYERS + l]; }
        float S = g * rstd * gate;
        float T = (bb - mean * g * rstd) * gate;
        ST[stat * 128 + col] = S;
        ST[stat * 128 + 64 + col] = T;
    }
}

// ---------------- host ----------------

static inline char* bump(char*& p, size_t bytes) {
    char* r = p;
    p += (bytes + 255) & ~(size_t)255;
    return r;
}

extern "C" void kernel_launch(void* const* d_in, const int* in_sizes, int n_in,
                              void* d_out, int out_size, void* d_ws, size_t ws_size,
                              hipStream_t stream) {
    const float* x      = (const float*)d_in[0];
    const int*   ei     = (const int*)d_in[1];
    const float* W      = (const float*)d_in[2];
    const float* bconv  = (const float*)d_in[3];
    const float* bn_g   = (const float*)d_in[4];
    const float* bn_b   = (const float*)d_in[5];
    const float* pw1    = (const float*)d_in[6];
    const float* pb1    = (const float*)d_in[7];
    const float* pw2    = (const float*)d_in[8];
    const float* pb2    = (const float*)d_in[9];
    const float* pbn_g  = (const float*)d_in[10];
    const float* pbn_b  = (const float*)d_in[11];
    const float* gating = (const float*)d_in[12];

    int n = in_sizes[0] / DIM;
    int E = in_sizes[1] / 2;
    int nbS  = (n + ROWS - 1) / ROWS;
    int nbFB = (n + ROWS_FB - 1) / ROWS_FB;
    int nb1024 = (n + 1023) / 1024;
    int nbkt = (n + 255) >> BKT_SHIFT;
    size_t n64b = (size_t)n * DIM * sizeof(float);
    size_t n64h = (size_t)n * DIM * sizeof(__half);
    int n4 = n * (DIM / 4);

    // carve workspace
    char* p = (char*)d_ws;
    float* h_ws     = (float*)bump(p, n64b);           // fallback only
    float* partials = (float*)bump(p, (size_t)nbFB * 6 * DIM * sizeof(float));
    float* ST       = (float*)bump(p, 6 * 128 * sizeof(float));
    float* gsum     = (float*)bump(p, (size_t)NLAYERS * NSTRIPE * 6 * DIM * sizeof(float));
    int*   bsum     = (int*)bump(p, (size_t)nb1024 * sizeof(int));
    int*   boff     = (int*)bump(p, (size_t)nb1024 * sizeof(int));
    int*   bcur     = (int*)bump(p, 257 * sizeof(int));
    int*   deg      = (int*)bump(p, (size_t)n * sizeof(int));
    int*   row_ptr  = (int*)bump(p, (size_t)(n + 1) * sizeof(int));
    int*   csr      = (int*)bump(p, (size_t)E * sizeof(int));
    float* aggr_f   = (float*)bump(p, n64b);   // fallback f32 aggr; fast path uses ah
    __half* ah = (__half*)bump(p, n64h);
    __half* yh = (__half*)bump(p, n64h);
    __half* uh = (__half*)bump(p, n64h);
    __half* vh = (__half*)bump(p, n64h);
    __half* hh = (__half*)bump(p, n64h);
    bool fast = ((size_t)(p - (char*)d_ws) <= ws_size);
    int2* part = (int2*)aggr_f;   // aliases fallback aggr; used only pre-loop

    const int* esrc = ei;
    const int* edst = ei + E;

    // CSR build + stats zero
    hipMemsetAsync(deg, 0, (size_t)n * sizeof(int), stream);
    hipMemsetAsync(gsum, 0, (size_t)NLAYERS * NSTRIPE * 6 * DIM * sizeof(float), stream);
    hist_k<<<(E + 255) / 256, 256, 0, stream>>>(edst, deg, E);
    scan_part_k<<<nb1024, 1024, 0, stream>>>(deg, row_ptr, bsum, n);
    scan_top_k<<<1, 1024, 0, stream>>>(bsum, boff, nb1024, row_ptr, n);
    scan_add_k<<<(n + 255) / 256, 256, 0, stream>>>(row_ptr, boff, deg, bcur, n);
    if (fast) {
        part_k<<<(E + 2047) / 2048, 256, 0, stream>>>(esrc, edst, bcur, part, E);
        bscat_k<<<nbkt, 256, 0, stream>>>(part, row_ptr, deg, csr, n);
        tohalf_k<<<(n4 + 255) / 256, 256, 0, stream>>>(x, hh, n4);
    } else {
        scatter_k<<<(E + 255) / 256, 256, 0, stream>>>(esrc, edst, deg, csr, E);
    }

    for (int l = 0; l < NLAYERS; l++) {
        const float* Wl  = W     + (size_t)l * DIM * DIM;
        const float* bl  = bconv + (size_t)l * DIM;
        const float* bgl = bn_g  + (size_t)l * DIM;
        const float* bbl = bn_b  + (size_t)l * DIM;
        const float* p1a = pw1 + ((size_t)0 * NLAYERS + l) * DIM * BOT;
        const float* p1b = pw1 + ((size_t)1 * NLAYERS + l) * DIM * BOT;
        const float* b1a = pb1 + ((size_t)0 * NLAYERS + l) * BOT;
        const float* b1b = pb1 + ((size_t)1 * NLAYERS + l) * BOT;
        const float* p2a = pw2 + ((size_t)0 * NLAYERS + l) * BOT * DIM;
        const float* p2b = pw2 + ((size_t)1 * NLAYERS + l) * BOT * DIM;
        const float* b2a = pb2 + ((size_t)0 * NLAYERS + l) * DIM;
        const float* b2b = pb2 + ((size_t)1 * NLAYERS + l) * DIM;
        const float* g0  = pbn_g + ((size_t)0 * NLAYERS + l) * DIM;
        const float* g1  = pbn_g + ((size_t)1 * NLAYERS + l) * DIM;
        const float* be0 = pbn_b + ((size_t)0 * NLAYERS + l) * DIM;
        const float* be1 = pbn_b + ((size_t)1 * NLAYERS + l) * DIM;

        float* gsl = gsum + (size_t)l * NSTRIPE * 6 * DIM;

        if (fast) {
            aggr_h_k<<<(n + 3) / 4, 256, 0, stream>>>(hh, row_ptr, csr, ah, n);

            stats_k<<<nbS, 512, 0, stream>>>(
                hh, ah, Wl, bl, p1a, b1a, p2a, b2a,
                p1b, b1b, p2b, b2b, gsl, yh, uh, vh, n);

            if (l < NLAYERS - 1)
                apply_k<0><<<(n4 + 255) / 256, 256, 0, stream>>>(
                    yh, uh, vh, gsl, bgl, bbl, g0, be0, g1, be1, gating, l, n,
                    nullptr, hh, n4);
            else
                apply_k<1><<<(n4 + 255) / 256, 256, 0, stream>>>(
                    yh, uh, vh, gsl, bgl, bbl, g0, be0, g1, be1, gating, l, n,
                    (float*)d_out, hh, n4);
        } else {
            const float* hin = (l == 0) ? x : h_ws;

            aggr_k<<<(n + 3) / 4, 256, 0, stream>>>(hin, row_ptr, csr, aggr_f, n);

            layer_k<0><<<nbFB, 256, 0, stream>>>(
                hin, aggr_f, Wl, bl, p1a, b1a, p2a, b2a, p1b, b1b, p2b, b2b,
                partials, nullptr, nullptr, n);

            reduce_fold_k<<<DIM, 256, 0, stream>>>(partials, nbFB, n, bgl, bbl,
                                                   g0, be0, g1, be1, gating, l, ST);

            if (l < NLAYERS - 1) {
                layer_k<2><<<nbFB, 256, 0, stream>>>(
                    hin, aggr_f, Wl, bl, p1a, b1a, p2a, b2a, p1b, b1b, p2b, b2b,
                    nullptr, ST, h_ws, n);
            } else {
                layer_k<1><<<nbFB, 256, 0, stream>>>(
                    hin, aggr_f, Wl, bl, p1a, b1a, p2a, b2a, p1b, b1b, p2b, b2b,
                    nullptr, ST, (float*)d_out, n);
            }
        }
    }
}